// Round 1
// baseline (148.788 us; speedup 1.0000x reference)
//
#include <hip/hip_runtime.h>
#include <math.h>

namespace {
constexpr int kS = 1024;                       // row length (fixed by problem)
constexpr float kEps = 1e-8f;
constexpr float kNegLogEps = 18.420680743952367f;     // -log(1e-8)
constexpr float kMaxEntropy = 6.9314718055994531f;    // log(1024)
constexpr float kInvMaxEntropy = 1.0f / 6.9314718055994531f;
constexpr float kTargetEntropy = 4.8520302639196169f; // log(1024)*0.7
constexpr float kBaseMaskProb = 0.15f;
}

// One wave (64 lanes) handles one row of 1024 f32; 4 rows per 256-thread block.
// All reductions are in-wave shfl_xor butterflies: no LDS, no barriers.
__global__ __launch_bounds__(256, 4)
void curriculum_kernel(const float* __restrict__ weights,
                       const float* __restrict__ noise,
                       float* __restrict__ out_w,
                       float* __restrict__ out_ent,
                       float* __restrict__ out_mrate,
                       float* __restrict__ out_tent,
                       int nrows)
{
    const int lane = threadIdx.x & 63;
    const int wid  = threadIdx.x >> 6;
    const int row  = blockIdx.x * 4 + wid;
    if (row >= nrows) return;

    const long long base = (long long)row * kS;
    const float4* __restrict__ wsrc = reinterpret_cast<const float4*>(weights + base);

    // ---- load 16 weights/lane (float4, coalesced: 16B/lane) ----
    float w[16];
    {
        float4 a = wsrc[lane];
        float4 b = wsrc[lane + 64];
        float4 c = wsrc[lane + 128];
        float4 d = wsrc[lane + 192];
        w[0]=a.x;  w[1]=a.y;  w[2]=a.z;  w[3]=a.w;
        w[4]=b.x;  w[5]=b.y;  w[6]=b.z;  w[7]=b.w;
        w[8]=c.x;  w[9]=c.y;  w[10]=c.z; w[11]=c.w;
        w[12]=d.x; w[13]=d.y; w[14]=d.z; w[15]=d.w;
    }

    // ---- row sum ----
    float s = ((w[0]+w[1])+(w[2]+w[3])) + ((w[4]+w[5])+(w[6]+w[7]))
            + ((w[8]+w[9])+(w[10]+w[11])) + ((w[12]+w[13])+(w[14]+w[15]));
    #pragma unroll
    for (int o = 1; o < 64; o <<= 1) s += __shfl_xor(s, o, 64);

    // ---- normalize (degenerate rows -> uniform) ----
    if (s < kEps) {
        #pragma unroll
        for (int i = 0; i < 16; ++i) w[i] = 1.0f / (float)kS;
    } else {
        const float inv = 1.0f / s;
        #pragma unroll
        for (int i = 0; i < 16; ++i) w[i] *= inv;
    }

    // ---- entropy = min(-sum w*log w, -log eps);  xlogy(0,0)=0 ----
    float ep = 0.0f;
    #pragma unroll
    for (int i = 0; i < 16; ++i)
        ep += (w[i] != 0.0f) ? w[i] * __logf(w[i]) : 0.0f;
    #pragma unroll
    for (int o = 1; o < 64; o <<= 1) ep += __shfl_xor(ep, o, 64);

    const float entropy   = fminf(-ep, kNegLogEps);
    const float nent      = fminf(fmaxf(entropy * kInvMaxEntropy, 0.0f), 1.0f);
    const float keep_prob = 1.0f - kBaseMaskProb * (1.0f - nent);

    // ---- load noise, build mask, count, masked-sum ----
    const float4* __restrict__ nsrc = reinterpret_cast<const float4*>(noise + base);
    float nz[16];
    {
        float4 a = nsrc[lane];
        float4 b = nsrc[lane + 64];
        float4 c = nsrc[lane + 128];
        float4 d = nsrc[lane + 192];
        nz[0]=a.x;  nz[1]=a.y;  nz[2]=a.z;  nz[3]=a.w;
        nz[4]=b.x;  nz[5]=b.y;  nz[6]=b.z;  nz[7]=b.w;
        nz[8]=c.x;  nz[9]=c.y;  nz[10]=c.z; nz[11]=c.w;
        nz[12]=d.x; nz[13]=d.y; nz[14]=d.z; nz[15]=d.w;
    }

    unsigned mask = 0u;
    float msum = 0.0f;
    int cnt = 0;
    #pragma unroll
    for (int i = 0; i < 16; ++i) {
        if (nz[i] < keep_prob) { mask |= (1u << i); msum += w[i]; ++cnt; }
    }

    // ---- local argmax (global element index; ties -> lowest index) ----
    float mxv = w[0];
    int   mxi = lane * 4;        // idx(i) = (i>>2)*256 + lane*4 + (i&3): monotone in i
    #pragma unroll
    for (int i = 1; i < 16; ++i) {
        const int idx = ((i >> 2) << 8) + lane * 4 + (i & 3);
        if (w[i] > mxv) { mxv = w[i]; mxi = idx; }
    }

    // ---- combined butterfly reduce: count, msum, argmax ----
    #pragma unroll
    for (int o = 1; o < 64; o <<= 1) {
        cnt  += __shfl_xor(cnt,  o, 64);
        msum += __shfl_xor(msum, o, 64);
        const float ov = __shfl_xor(mxv, o, 64);
        const int   oi = __shfl_xor(mxi, o, 64);
        if (ov > mxv || (ov == mxv && oi < mxi)) { mxv = ov; mxi = oi; }
    }

    // ---- min_active fallback: keep only the top-1 element ----
    if (cnt < 1) {
        mask = (((mxi >> 2) & 63) == lane) ? (1u << (((mxi >> 8) << 2) | (mxi & 3))) : 0u;
        msum = mxv;
        cnt  = 1;
    }

    // ---- renormalize kept entries (invalid rows fall back to w) ----
    const bool  valid = msum > kEps;
    const float invm  = valid ? 1.0f / msum : 0.0f;

    float f[16];
    #pragma unroll
    for (int i = 0; i < 16; ++i) {
        const float kept = ((mask >> i) & 1u) ? w[i] * invm : 0.0f;
        f[i] = valid ? kept : w[i];
    }

    float4* __restrict__ dst = reinterpret_cast<float4*>(out_w + base);
    dst[lane]       = make_float4(f[0],  f[1],  f[2],  f[3]);
    dst[lane + 64]  = make_float4(f[4],  f[5],  f[6],  f[7]);
    dst[lane + 128] = make_float4(f[8],  f[9],  f[10], f[11]);
    dst[lane + 192] = make_float4(f[12], f[13], f[14], f[15]);

    if (lane == 0) {
        out_ent[row]   = entropy;
        out_mrate[row] = 1.0f - (float)cnt * (1.0f / (float)kS);
        out_tent[row]  = kTargetEntropy;
    }
}

extern "C" void kernel_launch(void* const* d_in, const int* in_sizes, int n_in,
                              void* d_out, int out_size, void* d_ws, size_t ws_size,
                              hipStream_t stream)
{
    (void)n_in; (void)d_ws; (void)ws_size; (void)out_size;

    const float* weights = (const float*)d_in[0];
    const float* noise   = (const float*)d_in[1];
    const long long total = (long long)in_sizes[0];   // B*H*S*S
    const int nrows = (int)(total / kS);              // B*H*S

    float* out_w     = (float*)d_out;                 // [B,H,S,S]
    float* out_ent   = out_w + total;                 // [B,H,S]
    float* out_mrate = out_ent + nrows;               // [B,H,S]
    float* out_tent  = out_mrate + nrows;             // [B,H,S]

    const int blocks = (nrows + 3) / 4;               // 4 rows (waves) per block
    hipLaunchKernelGGL(curriculum_kernel, dim3(blocks), dim3(256), 0, stream,
                       weights, noise, out_w, out_ent, out_mrate, out_tent, nrows);
}

// Round 2
// 143.420 us; speedup vs baseline: 1.0374x; 1.0374x over previous
//
#include <hip/hip_runtime.h>
#include <math.h>

namespace {
constexpr int kS = 1024;                       // row length (fixed by problem)
constexpr float kEps = 1e-8f;
constexpr float kNegLogEps = 18.420680743952367f;     // -log(1e-8)
constexpr float kMaxEntropy = 6.9314718055994531f;    // log(1024)
constexpr float kInvMaxEntropy = 1.0f / 6.9314718055994531f;
constexpr float kTargetEntropy = 4.8520302639196169f; // log(1024)*0.7
constexpr float kBaseMaskProb = 0.15f;
typedef float f32x4 __attribute__((ext_vector_type(4)));
}

// One wave (64 lanes) per row of 1024 f32; 4 rows per 256-thread block.
// Chain-shortened version:
//  - entropy via H = ln(s) - (sum w*ln w)/s  -> logs don't wait on the sum,
//    and (s, plogp) reduce in ONE butterfly.
//  - final = w_raw / msum_raw (normalization cancels), valid <=> msum > eps*s.
//  - both input tiles loaded upfront (noise latency hidden under logs).
//  - argmax butterfly only on __ballot-empty rows (essentially never).
__global__ __launch_bounds__(256, 8)
void curriculum_kernel(const float* __restrict__ weights,
                       const float* __restrict__ noise,
                       float* __restrict__ out_w,
                       float* __restrict__ out_ent,
                       float* __restrict__ out_mrate,
                       float* __restrict__ out_tent,
                       int nrows)
{
    const int lane = threadIdx.x & 63;
    const int wid  = threadIdx.x >> 6;
    const int row  = blockIdx.x * 4 + wid;
    if (row >= nrows) return;

    const long long base = (long long)row * kS;
    const float4* __restrict__ wsrc = reinterpret_cast<const float4*>(weights + base);
    const float4* __restrict__ nsrc = reinterpret_cast<const float4*>(noise + base);

    // ---- issue ALL loads upfront: 8x global_load_dwordx4 in flight ----
    float4 a0 = wsrc[lane];
    float4 a1 = wsrc[lane + 64];
    float4 a2 = wsrc[lane + 128];
    float4 a3 = wsrc[lane + 192];
    float4 b0 = nsrc[lane];
    float4 b1 = nsrc[lane + 64];
    float4 b2 = nsrc[lane + 128];
    float4 b3 = nsrc[lane + 192];

    float w[16];
    w[0]=a0.x;  w[1]=a0.y;  w[2]=a0.z;  w[3]=a0.w;
    w[4]=a1.x;  w[5]=a1.y;  w[6]=a1.z;  w[7]=a1.w;
    w[8]=a2.x;  w[9]=a2.y;  w[10]=a2.z; w[11]=a2.w;
    w[12]=a3.x; w[13]=a3.y; w[14]=a3.z; w[15]=a3.w;

    // ---- local sum + plogp (raw weights; xlogy(0,.)=0 via fmax clamp) ----
    float s = 0.0f, p = 0.0f;
    #pragma unroll
    for (int i = 0; i < 16; ++i) {
        s += w[i];
        p += w[i] * __logf(fmaxf(w[i], 1e-37f));   // w==0 -> 0 * finite = 0
    }

    // ---- ONE combined butterfly for (s, p) ----
    #pragma unroll
    for (int o = 1; o < 64; o <<= 1) {
        s += __shfl_xor(s, o, 64);
        p += __shfl_xor(p, o, 64);
    }

    // ---- degenerate row (sum < eps): uniform weights (wave-uniform, ~never) ----
    if (s < kEps) {
        #pragma unroll
        for (int i = 0; i < 16; ++i) w[i] = 1.0f / (float)kS;
        s = 1.0f;
        p = -kMaxEntropy;   // => entropy = ln(1024)
    }

    const float inv_s   = 1.0f / s;
    const float entropy = fminf(__logf(s) - p * inv_s, kNegLogEps);
    const float nent    = fminf(fmaxf(entropy * kInvMaxEntropy, 0.0f), 1.0f);
    const float keep    = 1.0f - kBaseMaskProb * (1.0f - nent);

    // ---- mask from noise; local count + masked raw-sum ----
    float nz[16];
    nz[0]=b0.x;  nz[1]=b0.y;  nz[2]=b0.z;  nz[3]=b0.w;
    nz[4]=b1.x;  nz[5]=b1.y;  nz[6]=b1.z;  nz[7]=b1.w;
    nz[8]=b2.x;  nz[9]=b2.y;  nz[10]=b2.z; nz[11]=b2.w;
    nz[12]=b3.x; nz[13]=b3.y; nz[14]=b3.z; nz[15]=b3.w;

    unsigned mask = 0u;
    float msum = 0.0f, cntf = 0.0f;
    #pragma unroll
    for (int i = 0; i < 16; ++i) {
        if (nz[i] < keep) { mask |= (1u << i); msum += w[i]; cntf += 1.0f; }
    }

    const unsigned long long anyk = __ballot(mask != 0u);

    // ---- ONE butterfly for (cnt, msum) ----
    #pragma unroll
    for (int o = 1; o < 64; o <<= 1) {
        cntf += __shfl_xor(cntf, o, 64);
        msum += __shfl_xor(msum, o, 64);
    }

    // ---- min_active fallback (only when NO element kept; ~never taken) ----
    if (anyk == 0ull) {
        float mxv = w[0];
        int   mxi = lane * 4;      // idx(i) = (i>>2)*256 + lane*4 + (i&3), monotone in i
        #pragma unroll
        for (int i = 1; i < 16; ++i) {
            const int idx = ((i >> 2) << 8) + lane * 4 + (i & 3);
            if (w[i] > mxv) { mxv = w[i]; mxi = idx; }
        }
        #pragma unroll
        for (int o = 1; o < 64; o <<= 1) {
            const float ov = __shfl_xor(mxv, o, 64);
            const int   oi = __shfl_xor(mxi, o, 64);
            if (ov > mxv || (ov == mxv && oi < mxi)) { mxv = ov; mxi = oi; }
        }
        mask = (((mxi >> 2) & 63) == lane) ? (1u << (((mxi >> 8) << 2) | (mxi & 3))) : 0u;
        msum = mxv;
        cntf = 1.0f;
    }

    // ---- renormalize: final = w_raw/msum_raw (the row-sum cancels) ----
    const bool  valid = msum > kEps * s;           // msum_norm > eps
    const float scale = valid ? 1.0f / msum : inv_s;

    f32x4 f0, f1, f2, f3;
    #pragma unroll
    for (int i = 0; i < 16; ++i) {
        const float v = (valid && !((mask >> i) & 1u)) ? 0.0f : w[i] * scale;
        f32x4* dstv = (i < 4) ? &f0 : (i < 8) ? &f1 : (i < 12) ? &f2 : &f3;
        (*dstv)[i & 3] = v;
    }

    f32x4* __restrict__ dst = reinterpret_cast<f32x4*>(out_w + base);
    __builtin_nontemporal_store(f0, dst + lane);
    __builtin_nontemporal_store(f1, dst + lane + 64);
    __builtin_nontemporal_store(f2, dst + lane + 128);
    __builtin_nontemporal_store(f3, dst + lane + 192);

    // butterfly results are wave-uniform: spread the scalar stores over lanes
    if (lane == 0) out_ent[row]   = entropy;
    if (lane == 1) out_mrate[row] = 1.0f - cntf * (1.0f / (float)kS);
    if (lane == 2) out_tent[row]  = kTargetEntropy;
}

extern "C" void kernel_launch(void* const* d_in, const int* in_sizes, int n_in,
                              void* d_out, int out_size, void* d_ws, size_t ws_size,
                              hipStream_t stream)
{
    (void)n_in; (void)d_ws; (void)ws_size; (void)out_size;

    const float* weights = (const float*)d_in[0];
    const float* noise   = (const float*)d_in[1];
    const long long total = (long long)in_sizes[0];   // B*H*S*S
    const int nrows = (int)(total / kS);              // B*H*S

    float* out_w     = (float*)d_out;                 // [B,H,S,S]
    float* out_ent   = out_w + total;                 // [B,H,S]
    float* out_mrate = out_ent + nrows;               // [B,H,S]
    float* out_tent  = out_mrate + nrows;             // [B,H,S]

    const int blocks = (nrows + 3) / 4;               // 4 rows (waves) per block
    hipLaunchKernelGGL(curriculum_kernel, dim3(blocks), dim3(256), 0, stream,
                       weights, noise, out_w, out_ent, out_mrate, out_tent, nrows);
}